// Round 6
// baseline (273.814 us; speedup 1.0000x reference)
//
#include <hip/hip_runtime.h>
#include <hip/hip_bf16.h>

// GAE: h1 = relu(gcn(x,W1,b1)); z = gcn(h1,W2,b2); out = sigmoid(dot(Z[src], Q[dst]) + bb)
// where Q = Z @ Wb^T  (bilinear refactor, dst-side precompute).
// PULL aggregation over on-device CSR; gathered node matrices bf16 ROW-major.
// GEMMs: MFMA bf16 split-hi/lo f32 emulation. CSR build: histogram-free
// fixed-capacity bucket scatter; gemm1 + bucket_scatter overlapped in one
// heterogeneous launch; bucket_sort inlines the 391-count prefix.
// Round 13: Q-GEMM fused into decode; pair carries eid. (232 us)
// Round 14 (plane-major) REGRESSED -> reverted (half-line fetches).
// Round 15: 8-deep gather MLP in agg; 2-edge decode walk. (229.5 us)
// Round 16: SRC-SORTED edge order (bucket_sort does LDS counting sort by
// src>>7 before loc sort). (223.7 us)
// Round 17: PHASE-BARRIERED value-windowed walks. agg threads already walk
// src ascending; split the src space into PH windows (agg1 PH=4 -> 3.2MB of
// 12.8MB H1; agg2 PH=2 -> 3.2MB of 6.4MB H2) with __syncthreads between ->
// all co-resident blocks gather from the same L2-sized window at the same
// time. Pure scheduling: same j-order, f32 sums re-associate only at window
// boundaries.
// Round 11 (persistent tail + spin barriers) regressed 4.3x (L2 thrash) - reverted.

#define N_NODES 50000
#define BSH 7
#define BSZ 128                             // nodes per bucket
#define NBUCK ((N_NODES + BSZ - 1) / BSZ)   // 391
#define EPB 4096                            // edges per scatter block
#define CAP 3072                            // pair slots per bucket (22 sigma over mean 2048)
#define DSPLIT 4                            // decode blocks per bucket

typedef unsigned int u32;
typedef unsigned short u16;
typedef unsigned long long u64;

typedef __attribute__((ext_vector_type(8))) short bf16x8;
typedef __attribute__((ext_vector_type(4))) float f32x4;
union frag_u { bf16x8 f; u32 u[4]; uint4 v; };

__device__ __forceinline__ float bflo(u32 u) { return __uint_as_float(u << 16); }
__device__ __forceinline__ float bfhi(u32 u) { return __uint_as_float(u & 0xffff0000u); }
__device__ __forceinline__ u32 f2bf(float f) {  // RNE, returns low 16
    u32 b = __float_as_uint(f);
    return (b + 0x7fffu + ((b >> 16) & 1u)) >> 16;
}
__device__ __forceinline__ u32 pack2(float a, float b) { return f2bf(a) | (f2bf(b) << 16); }

// ================= fused: gemm1 (blocks < gblk) | bucket_scatter (rest) =================
__global__ __launch_bounds__(256) void gemm1_scatter(
        const float* __restrict__ X, const float* __restrict__ W,
        u16* __restrict__ O, int n_rows, int gblk,
        const int* __restrict__ src, const int* __restrict__ dst,
        int* __restrict__ bcur, u64* __restrict__ pair, int E) {
    constexpr int K = 128, NOUT = 128;
    constexpr int KP = K + 8;
    constexpr int NT = NOUT / 16;
    constexpr int KS = K / 32;
    __shared__ __align__(16) char smem[NOUT * KP * 2 * sizeof(u16)];
    int t = threadIdx.x;

    if ((int)blockIdx.x < gblk) {
        // ---------------- gemm1 path ----------------
        u16* Wt_hi = (u16*)smem;
        u16* Wt_lo = Wt_hi + NOUT * KP;
        for (int i4 = t; i4 < K * NOUT / 4; i4 += 256) {
            int k = (i4 * 4) / NOUT;
            int n0 = (i4 * 4) % NOUT;
            float4 w4 = *(const float4*)&W[(size_t)k * NOUT + n0];
            float wv[4] = {w4.x, w4.y, w4.z, w4.w};
#pragma unroll
            for (int q = 0; q < 4; q++) {
                u32 hi = f2bf(wv[q]);
                u32 lo = f2bf(wv[q] - bflo(hi));
                Wt_hi[(n0 + q) * KP + k] = (u16)hi;
                Wt_lo[(n0 + q) * KP + k] = (u16)lo;
            }
        }
        __syncthreads();

        int wave = t >> 6;
        int lane = t & 63;
        int m16 = lane & 15;
        int quad = lane >> 4;
        int row0 = blockIdx.x * 128 + wave * 32;

        f32x4 acc[2][NT] = {};
        for (int ks = 0; ks < KS; ks++) {
            frag_u a_hi[2], a_lo[2];
#pragma unroll
            for (int mt = 0; mt < 2; mt++) {
                int row = row0 + mt * 16 + m16;
                row = row < n_rows ? row : n_rows - 1;
                const float* Xp = X + (size_t)row * K + ks * 32 + quad * 8;
                float4 x0 = *(const float4*)Xp;
                float4 x1 = *(const float4*)(Xp + 4);
                float xv[8] = {x0.x, x0.y, x0.z, x0.w, x1.x, x1.y, x1.z, x1.w};
#pragma unroll
                for (int p = 0; p < 4; p++) {
                    u32 h0 = f2bf(xv[2 * p]), h1 = f2bf(xv[2 * p + 1]);
                    a_hi[mt].u[p] = h0 | (h1 << 16);
                    a_lo[mt].u[p] = pack2(xv[2 * p] - bflo(h0), xv[2 * p + 1] - bflo(h1));
                }
            }
#pragma unroll
            for (int nt = 0; nt < NT; nt++) {
                int n = nt * 16 + m16;
                frag_u b_hi, b_lo;
                b_hi.v = *(const uint4*)&Wt_hi[n * KP + ks * 32 + quad * 8];
                b_lo.v = *(const uint4*)&Wt_lo[n * KP + ks * 32 + quad * 8];
#pragma unroll
                for (int mt = 0; mt < 2; mt++) {
                    acc[mt][nt] = __builtin_amdgcn_mfma_f32_16x16x32_bf16(a_hi[mt].f, b_hi.f, acc[mt][nt], 0, 0, 0);
                    acc[mt][nt] = __builtin_amdgcn_mfma_f32_16x16x32_bf16(a_hi[mt].f, b_lo.f, acc[mt][nt], 0, 0, 0);
                    acc[mt][nt] = __builtin_amdgcn_mfma_f32_16x16x32_bf16(a_lo[mt].f, b_hi.f, acc[mt][nt], 0, 0, 0);
                }
            }
        }
#pragma unroll
        for (int mt = 0; mt < 2; mt++)
#pragma unroll
            for (int nt = 0; nt < NT; nt++)
#pragma unroll
                for (int r = 0; r < 4; r++) {
                    int row = row0 + mt * 16 + quad * 4 + r;
                    if (row < n_rows)
                        O[(size_t)row * NOUT + nt * 16 + m16] = (u16)f2bf(acc[mt][nt][r]);
                }
    } else {
        // ---------------- scatter path ----------------
        int* hist = (int*)smem;
        for (int i = t; i < NBUCK; i += 256) hist[i] = 0;
        __syncthreads();
        int base = ((int)blockIdx.x - gblk) * EPB;
        int s_[16], d_[16];
#pragma unroll
        for (int it = 0; it < 16; it++) {
            int e = base + it * 256 + t;
            if (e < E) {
                s_[it] = src[e];
                d_[it] = dst[e];
                atomicAdd(&hist[d_[it] >> BSH], 1);
            } else {
                d_[it] = -1;
            }
        }
        __syncthreads();
        for (int b = t; b < NBUCK; b += 256) {
            int c = hist[b];
            hist[b] = c ? (b * CAP + atomicAdd(&bcur[b], c)) : 0;  // absolute chunk base
        }
        __syncthreads();
#pragma unroll
        for (int it = 0; it < 16; it++) {
            if (d_[it] >= 0) {
                int b = d_[it] >> BSH;
                int off = atomicAdd(&hist[b], 1);
                int e = base + it * 256 + t;
                pair[off] = (u64)((u32)s_[it] | ((u32)(d_[it] & (BSZ - 1)) << 16))
                          | ((u64)(u32)e << 32);
            }
        }
    }
}

// ---------------- per-bucket: src-bucket sort + loc sort + row_ptr/dinv/inv ----------------
__global__ __launch_bounds__(256) void bucket_sort(u64* __restrict__ pair,
                                                   const int* __restrict__ bcur,
                                                   int* __restrict__ row_ptr,
                                                   int* __restrict__ col,
                                                   float* __restrict__ dinv,
                                                   float* __restrict__ inv, int n, int E) {
    __shared__ u64 prA[CAP];     // 24KB
    __shared__ u64 prB[CAP];     // 24KB
    __shared__ int ssum[256];
    __shared__ int histA[512];
    __shared__ int scA[512];
    __shared__ int cnt[BSZ];
    __shared__ int scn[BSZ];
    __shared__ int cur[BSZ];
    int t = threadIdx.x;
    int bucket = blockIdx.x;
    int base = bucket << BSH;
    int nn = min(BSZ, n - base);
    // inline exclusive prefix: b0 = sum(bcur[0..bucket-1])
    int accp = 0;
    for (int i = t; i < bucket; i += 256) accp += bcur[i];
    ssum[t] = accp;
    __syncthreads();
    for (int s = 128; s > 0; s >>= 1) {
        if (t < s) ssum[t] += ssum[t + s];
        __syncthreads();
    }
    int b0 = ssum[0];
    int cntE = bcur[bucket];
    int p0 = bucket * CAP;

    // ---- load pairs + src-bucket histogram ----
    histA[t] = 0;
    histA[t + 256] = 0;
    __syncthreads();
    for (int j = t; j < cntE; j += 256) {
        u64 p = pair[p0 + j];
        prA[j] = p;
        atomicAdd(&histA[(int)(p & 0xffffu) >> BSH], 1);
    }
    __syncthreads();
    // ---- exclusive scan over 512 bins ----
    int h0 = histA[t], h1 = histA[t + 256];
    scA[t] = h0;
    scA[t + 256] = h1;
    __syncthreads();
    for (int off = 1; off < 512; off <<= 1) {
        int a0 = (t >= off) ? scA[t - off] : 0;
        int a1 = (t + 256 >= off) ? scA[t + 256 - off] : 0;
        __syncthreads();
        scA[t] += a0;
        scA[t + 256] += a1;
        __syncthreads();
    }
    histA[t] = scA[t] - h0;          // exclusive -> cursor
    histA[t + 256] = scA[t + 256] - h1;
    __syncthreads();
    // ---- scatter by src-bucket: prA -> prB ----
    for (int j = t; j < cntE; j += 256) {
        u64 p = prA[j];
        int pos = atomicAdd(&histA[(int)(p & 0xffffu) >> BSH], 1);
        prB[pos] = p;
    }
    __syncthreads();
    // ---- write back src-sorted pair (decode consumes this order) ----
    for (int j = t; j < cntE; j += 256) pair[p0 + j] = prB[j];

    // ---- pass B: loc counting sort from prB ----
    if (t < BSZ) cnt[t] = 0;
    __syncthreads();
    for (int j = t; j < cntE; j += 256)
        atomicAdd(&cnt[(int)((prB[j] >> 16) & (BSZ - 1))], 1);
    __syncthreads();
    if (t < BSZ) scn[t] = cnt[t];
    __syncthreads();
    for (int off = 1; off < BSZ; off <<= 1) {
        int a = (t < BSZ && t >= off) ? scn[t - off] : 0;
        __syncthreads();
        if (t < BSZ) scn[t] += a;
        __syncthreads();
    }
    if (t < nn) {
        int excl = b0 + scn[t] - cnt[t];
        row_ptr[base + t] = excl;
        cur[t] = excl;
        float d = (float)cnt[t] + 1.0f;
        dinv[base + t] = rsqrtf(d);
        inv[base + t] = 1.0f / d;
    }
    if (t == 0 && bucket == NBUCK - 1) row_ptr[n] = E;
    __syncthreads();
    for (int j = t; j < cntE; j += 256) {
        u64 p = prB[j];
        int ln = (int)((p >> 16) & (BSZ - 1));
        int pos = atomicAdd(&cur[ln], 1);
        col[pos] = (int)(p & 0xffffu);
    }
}

// ---------------- MFMA GEMM (layer 2): O(bf16) = X(bf16) @ W(f32) ----------------
template <int K, int NOUT>
__global__ __launch_bounds__(256) void gemm_mfma_bf(const u16* __restrict__ Xv,
                                                    const float* __restrict__ W,
                                                    u16* __restrict__ O, int n_rows) {
    constexpr int KP = K + 8;
    constexpr int NT = NOUT / 16;
    constexpr int KS = K / 32;
    __shared__ __align__(16) u16 Wt_hi[NOUT * KP];
    __shared__ __align__(16) u16 Wt_lo[NOUT * KP];
    int t = threadIdx.x;
    for (int i4 = t; i4 < K * NOUT / 4; i4 += 256) {
        int k = (i4 * 4) / NOUT;
        int n0 = (i4 * 4) % NOUT;
        float4 w4 = *(const float4*)&W[(size_t)k * NOUT + n0];
        float wv[4] = {w4.x, w4.y, w4.z, w4.w};
#pragma unroll
        for (int q = 0; q < 4; q++) {
            u32 hi = f2bf(wv[q]);
            u32 lo = f2bf(wv[q] - bflo(hi));
            Wt_hi[(n0 + q) * KP + k] = (u16)hi;
            Wt_lo[(n0 + q) * KP + k] = (u16)lo;
        }
    }
    __syncthreads();

    int wave = t >> 6;
    int lane = t & 63;
    int m16 = lane & 15;
    int quad = lane >> 4;
    int row0 = blockIdx.x * 128 + wave * 32;

    f32x4 acc[2][NT] = {};
    for (int ks = 0; ks < KS; ks++) {
        frag_u a_hi[2];
#pragma unroll
        for (int mt = 0; mt < 2; mt++) {
            int row = row0 + mt * 16 + m16;
            row = row < n_rows ? row : n_rows - 1;
            a_hi[mt].v = *(const uint4*)(Xv + (size_t)row * K + ks * 32 + quad * 8);
        }
#pragma unroll
        for (int nt = 0; nt < NT; nt++) {
            int n = nt * 16 + m16;
            frag_u b_hi, b_lo;
            b_hi.v = *(const uint4*)&Wt_hi[n * KP + ks * 32 + quad * 8];
            b_lo.v = *(const uint4*)&Wt_lo[n * KP + ks * 32 + quad * 8];
#pragma unroll
            for (int mt = 0; mt < 2; mt++) {
                acc[mt][nt] = __builtin_amdgcn_mfma_f32_16x16x32_bf16(a_hi[mt].f, b_hi.f, acc[mt][nt], 0, 0, 0);
                acc[mt][nt] = __builtin_amdgcn_mfma_f32_16x16x32_bf16(a_hi[mt].f, b_lo.f, acc[mt][nt], 0, 0, 0);
            }
        }
    }
#pragma unroll
    for (int mt = 0; mt < 2; mt++)
#pragma unroll
        for (int nt = 0; nt < NT; nt++)
#pragma unroll
            for (int r = 0; r < 4; r++) {
                int row = row0 + mt * 16 + quad * 4 + r;
                if (row < n_rows)
                    O[(size_t)row * NOUT + nt * 16 + m16] = (u16)f2bf(acc[mt][nt][r]);
            }
}

// ---------------- pull aggregation + self-loop + bias (+relu), bf16 in/out ----------------
// Phase-barriered value-windowed walk: col is src-ascending per node; the src
// space is split into PH windows with __syncthreads between -> co-resident
// blocks gather from the same ~3.2MB window concurrently (L2-resident).
// 8 gathers issued per iteration inside a window.
template <int C, bool RELU, int PH>
__global__ __launch_bounds__(256) void agg_pull(const u16* __restrict__ H,
                                                const int* __restrict__ row_ptr,
                                                const int* __restrict__ col,
                                                const float* __restrict__ dinv,
                                                const float* __restrict__ inv,
                                                const float* __restrict__ b,
                                                u16* __restrict__ O, int n) {
    constexpr int TPN = C / 8;
    const uint4* Hv = (const uint4*)H;
    int tid = blockIdx.x * 256 + threadIdx.x;
    int node = tid / TPN;
    bool act = node < n;
    int part = tid % TPN;
    int c8 = part * 8;
    float dn = 0.f, iv = 0.f;
    float acc[8] = {};
    int j = 0, end = 0;
    if (act) {
        dn = dinv[node];
        iv = inv[node];
        uint4 h = Hv[(size_t)node * TPN + part];
        acc[0] = bflo(h.x) * iv + b[c8 + 0];
        acc[1] = bfhi(h.x) * iv + b[c8 + 1];
        acc[2] = bflo(h.y) * iv + b[c8 + 2];
        acc[3] = bfhi(h.y) * iv + b[c8 + 3];
        acc[4] = bflo(h.z) * iv + b[c8 + 4];
        acc[5] = bfhi(h.z) * iv + b[c8 + 5];
        acc[6] = bflo(h.w) * iv + b[c8 + 6];
        acc[7] = bfhi(h.w) * iv + b[c8 + 7];
        j = row_ptr[node];
        end = row_ptr[node + 1];
    }
    const int wstep = (n + PH - 1) / PH;
#pragma unroll 1
    for (int ph = 1; ph <= PH; ph++) {
        int e2 = end;
        if (ph < PH) {
            int bound = ph * wstep;
            e2 = j;
            while (e2 < end && col[e2] < bound) e2++;
        }
        for (; j + 7 < e2; j += 8) {
            int s0 = col[j],     s1 = col[j + 1], s2 = col[j + 2], s3 = col[j + 3];
            int s4 = col[j + 4], s5 = col[j + 5], s6 = col[j + 6], s7 = col[j + 7];
            float n0 = dn * dinv[s0], n1 = dn * dinv[s1];
            float n2 = dn * dinv[s2], n3 = dn * dinv[s3];
            float n4 = dn * dinv[s4], n5 = dn * dinv[s5];
            float n6 = dn * dinv[s6], n7 = dn * dinv[s7];
            uint4 v0 = Hv[(size_t)s0 * TPN + part];
            uint4 v1 = Hv[(size_t)s1 * TPN + part];
            uint4 v2 = Hv[(size_t)s2 * TPN + part];
            uint4 v3 = Hv[(size_t)s3 * TPN + part];
            uint4 v4 = Hv[(size_t)s4 * TPN + part];
            uint4 v5 = Hv[(size_t)s5 * TPN + part];
            uint4 v6 = Hv[(size_t)s6 * TPN + part];
            uint4 v7 = Hv[(size_t)s7 * TPN + part];
            acc[0] += bflo(v0.x) * n0 + bflo(v1.x) * n1 + bflo(v2.x) * n2 + bflo(v3.x) * n3;
            acc[1] += bfhi(v0.x) * n0 + bfhi(v1.x) * n1 + bfhi(v2.x) * n2 + bfhi(v3.x) * n3;
            acc[2] += bflo(v0.y) * n0 + bflo(v1.y) * n1 + bflo(v2.y) * n2 + bflo(v3.y) * n3;
            acc[3] += bfhi(v0.y) * n0 + bfhi(v1.y) * n1 + bfhi(v2.y) * n2 + bfhi(v3.y) * n3;
            acc[4] += bflo(v0.z) * n0 + bflo(v1.z) * n1 + bflo(v2.z) * n2 + bflo(v3.z) * n3;
            acc[5] += bfhi(v0.z) * n0 + bfhi(v1.z) * n1 + bfhi(v2.z) * n2 + bfhi(v3.z) * n3;
            acc[6] += bflo(v0.w) * n0 + bflo(v1.w) * n1 + bflo(v2.w) * n2 + bflo(v3.w) * n3;
            acc[7] += bfhi(v0.w) * n0 + bfhi(v1.w) * n1 + bfhi(v2.w) * n2 + bfhi(v3.w) * n3;
            acc[0] += bflo(v4.x) * n4 + bflo(v5.x) * n5 + bflo(v6.x) * n6 + bflo(v7.x) * n7;
            acc[1] += bfhi(v4.x) * n4 + bfhi(v5.x) * n5 + bfhi(v6.x) * n6 + bfhi(v7.x) * n7;
            acc[2] += bflo(v4.y) * n4 + bflo(v5.y) * n5 + bflo(v6.y) * n6 + bflo(v7.y) * n7;
            acc[3] += bfhi(v4.y) * n4 + bfhi(v5.y) * n5 + bfhi(v6.y) * n6 + bfhi(v7.y) * n7;
            acc[4] += bflo(v4.z) * n4 + bflo(v5.z) * n5 + bflo(v6.z) * n6 + bflo(v7.z) * n7;
            acc[5] += bfhi(v4.z) * n4 + bfhi(v5.z) * n5 + bfhi(v6.z) * n6 + bfhi(v7.z) * n7;
            acc[6] += bflo(v4.w) * n4 + bflo(v5.w) * n5 + bflo(v6.w) * n6 + bflo(v7.w) * n7;
            acc[7] += bfhi(v4.w) * n4 + bfhi(v5.w) * n5 + bfhi(v6.w) * n6 + bfhi(v7.w) * n7;
        }
        for (; j + 3 < e2; j += 4) {
            int s0 = col[j], s1 = col[j + 1], s2 = col[j + 2], s3 = col[j + 3];
            float n0 = dn * dinv[s0], n1 = dn * dinv[s1];
            float n2 = dn * dinv[s2], n3 = dn * dinv[s3];
            uint4 v0 = Hv[(size_t)s0 * TPN + part];
            uint4 v1 = Hv[(size_t)s1 * TPN + part];
            uint4 v2 = Hv[(size_t)s2 * TPN + part];
            uint4 v3 = Hv[(size_t)s3 * TPN + part];
            acc[0] += bflo(v0.x) * n0 + bflo(v1.x) * n1 + bflo(v2.x) * n2 + bflo(v3.x) * n3;
            acc[1] += bfhi(v0.x) * n0 + bfhi(v1.x) * n1 + bfhi(v2.x) * n2 + bfhi(v3.x) * n3;
            acc[2] += bflo(v0.y) * n0 + bflo(v1.y) * n1 + bflo(v2.y) * n2 + bflo(v3.y) * n3;
            acc[3] += bfhi(v0.y) * n0 + bfhi(v1.y) * n1 + bfhi(v2.y) * n2 + bfhi(v3.y) * n3;
            acc[4] += bflo(v0.z) * n0 + bflo(v1.z) * n1 + bflo(v2.z) * n2 + bflo(v3.z) * n3;
            acc[5] += bfhi(v0.z) * n0 + bfhi(v1.z) * n1 + bfhi(v2.z) * n2 + bfhi(v3.z) * n3;
            acc[6] += bflo(v0.w) * n0 + bflo(v1.w) * n1 + bflo(v2.w) * n2 + bflo(v3.w) * n3;
            acc[7] += bfhi(v0.w) * n0 + bfhi(v1.w) * n1 + bfhi(v2.w) * n2 + bfhi(v3.w) * n3;
        }
        for (; j < e2; j++) {
            int s = col[j];
            float nm = dn * dinv[s];
            uint4 v = Hv[(size_t)s * TPN + part];
            acc[0] += bflo(v.x) * nm; acc[1] += bfhi(v.x) * nm;
            acc[2] += bflo(v.y) * nm; acc[3] += bfhi(v.y) * nm;
            acc[4] += bflo(v.z) * nm; acc[5] += bfhi(v.z) * nm;
            acc[6] += bflo(v.w) * nm; acc[7] += bfhi(v.w) * nm;
        }
        if (ph < PH) __syncthreads();
    }
    if (!act) return;
    if (RELU) {
#pragma unroll
        for (int i = 0; i < 8; i++) acc[i] = fmaxf(acc[i], 0.f);
    }
    uint4 o;
    o.x = pack2(acc[0], acc[1]);
    o.y = pack2(acc[2], acc[3]);
    o.z = pack2(acc[4], acc[5]);
    o.w = pack2(acc[6], acc[7]);
    ((uint4*)O)[(size_t)node * TPN + part] = o;
}

// ---------------- decode with fused per-bucket Q-GEMM ----------------
__global__ __launch_bounds__(256) void decode_fused(const u16* __restrict__ Z,
                                                    const float* __restrict__ Wb,
                                                    const u64* __restrict__ pair,
                                                    const int* __restrict__ bcur,
                                                    const float* __restrict__ bb,
                                                    float* __restrict__ out, int n) {
    constexpr int K = 64, NOUT = 64;
    constexpr int KP = K + 8;   // 72
    constexpr int QP = 72;      // padded Q row (u16), 144B = 9 banks stagger
    __shared__ __align__(16) u16 Wt_hi[NOUT * KP];
    __shared__ __align__(16) u16 Wt_lo[NOUT * KP];
    __shared__ __align__(16) u16 Qs[BSZ * QP];
    int t = threadIdx.x;
    int bucket = blockIdx.x / DSPLIT;
    int part = blockIdx.x % DSPLIT;
    int base = bucket << BSH;

    // stage Wb^T hi/lo:  Wt[n*KP+k] <- split(Wb[n][k])   (Wb row-major [64][64])
    for (int i4 = t; i4 < K * NOUT / 4; i4 += 256) {
        int nn_ = (i4 * 4) / K;
        int k0 = (i4 * 4) % K;
        float4 w4 = *(const float4*)&Wb[(size_t)nn_ * K + k0];
        float wv[4] = {w4.x, w4.y, w4.z, w4.w};
#pragma unroll
        for (int q = 0; q < 4; q++) {
            u32 hi = f2bf(wv[q]);
            u32 lo = f2bf(wv[q] - bflo(hi));
            Wt_hi[nn_ * KP + k0 + q] = (u16)hi;
            Wt_lo[nn_ * KP + k0 + q] = (u16)lo;
        }
    }
    __syncthreads();

    // Q tile: 4 waves x 32 rows each, 64 cols, K=64 (2 ks steps)
    {
        int wave = t >> 6;
        int lane = t & 63;
        int m16 = lane & 15;
        int quad = lane >> 4;
        int row0 = wave * 32;
        f32x4 acc[2][4] = {};
        for (int ks = 0; ks < 2; ks++) {
            frag_u a[2];
#pragma unroll
            for (int mt = 0; mt < 2; mt++) {
                int node = base + row0 + mt * 16 + m16;
                node = node < n ? node : n - 1;
                a[mt].v = *(const uint4*)(Z + (size_t)node * K + ks * 32 + quad * 8);
            }
#pragma unroll
            for (int nt = 0; nt < 4; nt++) {
                int nc = nt * 16 + m16;
                frag_u b_hi, b_lo;
                b_hi.v = *(const uint4*)&Wt_hi[nc * KP + ks * 32 + quad * 8];
                b_lo.v = *(const uint4*)&Wt_lo[nc * KP + ks * 32 + quad * 8];
#pragma unroll
                for (int mt = 0; mt < 2; mt++) {
                    acc[mt][nt] = __builtin_amdgcn_mfma_f32_16x16x32_bf16(a[mt].f, b_hi.f, acc[mt][nt], 0, 0, 0);
                    acc[mt][nt] = __builtin_amdgcn_mfma_f32_16x16x32_bf16(a[mt].f, b_lo.f, acc[mt][nt], 0, 0, 0);
                }
            }
        }
#pragma unroll
        for (int mt = 0; mt < 2; mt++)
#pragma unroll
            for (int nt = 0; nt < 4; nt++)
#pragma unroll
                for (int r = 0; r < 4; r++) {
                    int rl = row0 + mt * 16 + quad * 4 + r;
                    Qs[rl * QP + nt * 16 + m16] = (u16)f2bf(acc[mt][nt][r]);
                }
    }
    __syncthreads();

    // edge walk: 2 edges per 8-lane group per iteration (src-sorted pair)
    const uint4* Zv = (const uint4*)Z;
    int cntE = bcur[bucket];
    int p0 = bucket * CAP;
    int chunk = (cntE + DSPLIT - 1) / DSPLIT;
    int s0 = part * chunk;
    int s1 = min(s0 + chunk, cntE);
    float bbv = bb[0];
    int lane8 = t & 7;
    int grp = t >> 3;   // 0..31
    for (int j = s0 + grp * 2; j < s1; j += 64) {
        u64 pA = pair[p0 + j];
        bool has2 = (j + 1) < s1;
        u64 pB = has2 ? pair[p0 + j + 1] : pA;
        int sA = (int)(pA & 0xffffu);
        int sB = (int)(pB & 0xffffu);
        int locA = (int)((pA >> 16) & (BSZ - 1));
        int locB = (int)((pB >> 16) & (BSZ - 1));
        uint4 zA = Zv[(size_t)sA * 8 + lane8];
        uint4 zB = Zv[(size_t)sB * 8 + lane8];
        uint4 qA = *(const uint4*)&Qs[locA * QP + lane8 * 8];
        uint4 qB = *(const uint4*)&Qs[locB * QP + lane8 * 8];
        float dA = bflo(zA.x) * bflo(qA.x) + bfhi(zA.x) * bfhi(qA.x)
                 + bflo(zA.y) * bflo(qA.y) + bfhi(zA.y) * bfhi(qA.y)
                 + bflo(zA.z) * bflo(qA.z) + bfhi(zA.z) * bfhi(qA.z)
                 + bflo(zA.w) * bflo(qA.w) + bfhi(zA.w) * bfhi(qA.w);
        float dB = bflo(zB.x) * bflo(qB.x) + bfhi(zB.x) * bfhi(qB.x)
                 + bflo(zB.y) * bflo(qB.y) + bfhi(zB.y) * bfhi(qB.y)
                 + bflo(zB.z) * bflo(qB.z) + bfhi(zB.z) * bfhi(qB.z)
                 + bflo(zB.w) * bflo(qB.w) + bfhi(zB.w) * bfhi(qB.w);
        dA += __shfl_down(dA, 4, 8);
        dA += __shfl_down(dA, 2, 8);
        dA += __shfl_down(dA, 1, 8);
        dB += __shfl_down(dB, 4, 8);
        dB += __shfl_down(dB, 2, 8);
        dB += __shfl_down(dB, 1, 8);
        if (lane8 == 0) {
            out[(int)(pA >> 32)] = 1.0f / (1.0f + expf(-(dA + bbv)));
            if (has2) out[(int)(pB >> 32)] = 1.0f / (1.0f + expf(-(dB + bbv)));
        }
    }
}

extern "C" void kernel_launch(void* const* d_in, const int* in_sizes, int n_in,
                              void* d_out, int out_size, void* d_ws, size_t ws_size,
                              hipStream_t stream) {
    const float* x  = (const float*)d_in[0];
    const int*   ei = (const int*)d_in[1];
    const float* W1 = (const float*)d_in[2];
    const float* b1 = (const float*)d_in[3];
    const float* W2 = (const float*)d_in[4];
    const float* b2 = (const float*)d_in[5];
    const float* Wb = (const float*)d_in[6];
    const float* bb = (const float*)d_in[7];
    float* out = (float*)d_out;

    const int N = N_NODES;
    const int E = in_sizes[1] / 2;
    const int* src = ei;
    const int* dst = ei + E;
    const int GBLK = (N + 127) / 128;        // 391 gemm blocks
    const int SBLK = (E + EPB - 1) / EPB;    // 196 scatter blocks

    // workspace layout
    char* w = (char*)d_ws;
    int*   bcur    = (int*)w;   w += (size_t)512 * 4;
    int*   row_ptr = (int*)w;   w += (size_t)(N + 1) * 4;
    int*   col     = (int*)w;   w += (size_t)E * 4;
    w = (char*)(((size_t)w + 15) & ~(size_t)15);
    u64*   pair    = (u64*)w;   w += (size_t)NBUCK * CAP * 8;
    float* dinv    = (float*)w; w += (size_t)N * 4;
    float* inv     = (float*)w; w += (size_t)N * 4;
    w = (char*)(((size_t)w + 15) & ~(size_t)15);
    u16* bufA = (u16*)w;        w += (size_t)N * 128 * 2;  // H1; later H2
    u16* bufB = (u16*)w;        w += (size_t)N * 128 * 2;  // h1
    u16* bufC = (u16*)w;                                   // Z

    u16* H1 = bufA;
    u16* h1 = bufB;
    u16* H2 = bufA;                  // H1 dead after agg1
    u16* Z  = bufC;

    // CSR build front-end overlapped with layer-1 GEMM (independent work)
    hipMemsetAsync(bcur, 0, 512 * 4, stream);
    gemm1_scatter<<<GBLK + SBLK, 256, 0, stream>>>(x, W1, H1, N, GBLK,
                                                   src, dst, bcur, pair, E);
    bucket_sort<<<NBUCK, 256, 0, stream>>>(pair, bcur, row_ptr, col, dinv, inv, N, E);

    // layer 1 aggregation (4 src-window phases)
    agg_pull<128, true, 4><<<((size_t)N * 16 + 255) / 256, 256, 0, stream>>>(
        H1, row_ptr, col, dinv, inv, b1, h1, N);

    // layer 2
    gemm_mfma_bf<128, 64><<<GBLK, 256, 0, stream>>>(h1, W2, H2, N);
    agg_pull<64, false, 2><<<((size_t)N * 8 + 255) / 256, 256, 0, stream>>>(
        H2, row_ptr, col, dinv, inv, b2, Z, N);

    // decode: per-bucket fused Q-GEMM (LDS) + bilinear + sigmoid
    decode_fused<<<NBUCK * DSPLIT, 256, 0, stream>>>(Z, Wb, pair, bcur, bb, out, N);
}

// Round 7
// 239.856 us; speedup vs baseline: 1.1416x; 1.1416x over previous
//
#include <hip/hip_runtime.h>
#include <hip/hip_bf16.h>

// GAE: h1 = relu(gcn(x,W1,b1)); z = gcn(h1,W2,b2); out = sigmoid(dot(Z[src], Q[dst]) + bb)
// where Q = Z @ Wb^T  (bilinear refactor, dst-side precompute).
// PULL aggregation over on-device CSR; gathered node matrices bf16 ROW-major.
// GEMMs: MFMA bf16 split-hi/lo f32 emulation. CSR build: histogram-free
// fixed-capacity bucket scatter; gemm1 + bucket_scatter overlapped in one
// heterogeneous launch; bucket_sort inlines the 391-count prefix.
// Round 13: Q-GEMM fused into decode; pair carries eid. (232 us)
// Round 14 (plane-major) REGRESSED -> reverted (half-line fetches).
// Round 15: 8-deep gather MLP in agg; 2-edge decode walk. (229.5 us)
// Round 16: SRC-SORTED edge order (bucket_sort LDS counting sort by src>>7
// before loc sort). (223.7 us)
// Round 17 (phase-barriered windows) REGRESSED 223.7->273.8: __syncthreads
// gates each phase on the slowest thread (agg 82us, occ 40%); FETCH showed
// ~50% of gather traffic already L2-hits naturally. REVERTED.
// Round 18: (a) agg 16-deep gather pipeline (four 4-wide blocks, same
// association -> bit-identical); (b) decode DSPLIT 4->8 (2x block parallelism
// for Z-gather latency hiding; per-bucket Q redundancy is L2-hot and cheap).
// Round 11 (persistent tail + spin barriers) regressed 4.3x (L2 thrash) - reverted.

#define N_NODES 50000
#define BSH 7
#define BSZ 128                             // nodes per bucket
#define NBUCK ((N_NODES + BSZ - 1) / BSZ)   // 391
#define EPB 4096                            // edges per scatter block
#define CAP 3072                            // pair slots per bucket (22 sigma over mean 2048)
#define DSPLIT 8                            // decode blocks per bucket

typedef unsigned int u32;
typedef unsigned short u16;
typedef unsigned long long u64;

typedef __attribute__((ext_vector_type(8))) short bf16x8;
typedef __attribute__((ext_vector_type(4))) float f32x4;
union frag_u { bf16x8 f; u32 u[4]; uint4 v; };

__device__ __forceinline__ float bflo(u32 u) { return __uint_as_float(u << 16); }
__device__ __forceinline__ float bfhi(u32 u) { return __uint_as_float(u & 0xffff0000u); }
__device__ __forceinline__ u32 f2bf(float f) {  // RNE, returns low 16
    u32 b = __float_as_uint(f);
    return (b + 0x7fffu + ((b >> 16) & 1u)) >> 16;
}
__device__ __forceinline__ u32 pack2(float a, float b) { return f2bf(a) | (f2bf(b) << 16); }

// ================= fused: gemm1 (blocks < gblk) | bucket_scatter (rest) =================
__global__ __launch_bounds__(256) void gemm1_scatter(
        const float* __restrict__ X, const float* __restrict__ W,
        u16* __restrict__ O, int n_rows, int gblk,
        const int* __restrict__ src, const int* __restrict__ dst,
        int* __restrict__ bcur, u64* __restrict__ pair, int E) {
    constexpr int K = 128, NOUT = 128;
    constexpr int KP = K + 8;
    constexpr int NT = NOUT / 16;
    constexpr int KS = K / 32;
    __shared__ __align__(16) char smem[NOUT * KP * 2 * sizeof(u16)];
    int t = threadIdx.x;

    if ((int)blockIdx.x < gblk) {
        // ---------------- gemm1 path ----------------
        u16* Wt_hi = (u16*)smem;
        u16* Wt_lo = Wt_hi + NOUT * KP;
        for (int i4 = t; i4 < K * NOUT / 4; i4 += 256) {
            int k = (i4 * 4) / NOUT;
            int n0 = (i4 * 4) % NOUT;
            float4 w4 = *(const float4*)&W[(size_t)k * NOUT + n0];
            float wv[4] = {w4.x, w4.y, w4.z, w4.w};
#pragma unroll
            for (int q = 0; q < 4; q++) {
                u32 hi = f2bf(wv[q]);
                u32 lo = f2bf(wv[q] - bflo(hi));
                Wt_hi[(n0 + q) * KP + k] = (u16)hi;
                Wt_lo[(n0 + q) * KP + k] = (u16)lo;
            }
        }
        __syncthreads();

        int wave = t >> 6;
        int lane = t & 63;
        int m16 = lane & 15;
        int quad = lane >> 4;
        int row0 = blockIdx.x * 128 + wave * 32;

        f32x4 acc[2][NT] = {};
        for (int ks = 0; ks < KS; ks++) {
            frag_u a_hi[2], a_lo[2];
#pragma unroll
            for (int mt = 0; mt < 2; mt++) {
                int row = row0 + mt * 16 + m16;
                row = row < n_rows ? row : n_rows - 1;
                const float* Xp = X + (size_t)row * K + ks * 32 + quad * 8;
                float4 x0 = *(const float4*)Xp;
                float4 x1 = *(const float4*)(Xp + 4);
                float xv[8] = {x0.x, x0.y, x0.z, x0.w, x1.x, x1.y, x1.z, x1.w};
#pragma unroll
                for (int p = 0; p < 4; p++) {
                    u32 h0 = f2bf(xv[2 * p]), h1 = f2bf(xv[2 * p + 1]);
                    a_hi[mt].u[p] = h0 | (h1 << 16);
                    a_lo[mt].u[p] = pack2(xv[2 * p] - bflo(h0), xv[2 * p + 1] - bflo(h1));
                }
            }
#pragma unroll
            for (int nt = 0; nt < NT; nt++) {
                int n = nt * 16 + m16;
                frag_u b_hi, b_lo;
                b_hi.v = *(const uint4*)&Wt_hi[n * KP + ks * 32 + quad * 8];
                b_lo.v = *(const uint4*)&Wt_lo[n * KP + ks * 32 + quad * 8];
#pragma unroll
                for (int mt = 0; mt < 2; mt++) {
                    acc[mt][nt] = __builtin_amdgcn_mfma_f32_16x16x32_bf16(a_hi[mt].f, b_hi.f, acc[mt][nt], 0, 0, 0);
                    acc[mt][nt] = __builtin_amdgcn_mfma_f32_16x16x32_bf16(a_hi[mt].f, b_lo.f, acc[mt][nt], 0, 0, 0);
                    acc[mt][nt] = __builtin_amdgcn_mfma_f32_16x16x32_bf16(a_lo[mt].f, b_hi.f, acc[mt][nt], 0, 0, 0);
                }
            }
        }
#pragma unroll
        for (int mt = 0; mt < 2; mt++)
#pragma unroll
            for (int nt = 0; nt < NT; nt++)
#pragma unroll
                for (int r = 0; r < 4; r++) {
                    int row = row0 + mt * 16 + quad * 4 + r;
                    if (row < n_rows)
                        O[(size_t)row * NOUT + nt * 16 + m16] = (u16)f2bf(acc[mt][nt][r]);
                }
    } else {
        // ---------------- scatter path ----------------
        int* hist = (int*)smem;
        for (int i = t; i < NBUCK; i += 256) hist[i] = 0;
        __syncthreads();
        int base = ((int)blockIdx.x - gblk) * EPB;
        int s_[16], d_[16];
#pragma unroll
        for (int it = 0; it < 16; it++) {
            int e = base + it * 256 + t;
            if (e < E) {
                s_[it] = src[e];
                d_[it] = dst[e];
                atomicAdd(&hist[d_[it] >> BSH], 1);
            } else {
                d_[it] = -1;
            }
        }
        __syncthreads();
        for (int b = t; b < NBUCK; b += 256) {
            int c = hist[b];
            hist[b] = c ? (b * CAP + atomicAdd(&bcur[b], c)) : 0;  // absolute chunk base
        }
        __syncthreads();
#pragma unroll
        for (int it = 0; it < 16; it++) {
            if (d_[it] >= 0) {
                int b = d_[it] >> BSH;
                int off = atomicAdd(&hist[b], 1);
                int e = base + it * 256 + t;
                pair[off] = (u64)((u32)s_[it] | ((u32)(d_[it] & (BSZ - 1)) << 16))
                          | ((u64)(u32)e << 32);
            }
        }
    }
}

// ---------------- per-bucket: src-bucket sort + loc sort + row_ptr/dinv/inv ----------------
__global__ __launch_bounds__(256) void bucket_sort(u64* __restrict__ pair,
                                                   const int* __restrict__ bcur,
                                                   int* __restrict__ row_ptr,
                                                   int* __restrict__ col,
                                                   float* __restrict__ dinv,
                                                   float* __restrict__ inv, int n, int E) {
    __shared__ u64 prA[CAP];     // 24KB
    __shared__ u64 prB[CAP];     // 24KB
    __shared__ int ssum[256];
    __shared__ int histA[512];
    __shared__ int scA[512];
    __shared__ int cnt[BSZ];
    __shared__ int scn[BSZ];
    __shared__ int cur[BSZ];
    int t = threadIdx.x;
    int bucket = blockIdx.x;
    int base = bucket << BSH;
    int nn = min(BSZ, n - base);
    // inline exclusive prefix: b0 = sum(bcur[0..bucket-1])
    int accp = 0;
    for (int i = t; i < bucket; i += 256) accp += bcur[i];
    ssum[t] = accp;
    __syncthreads();
    for (int s = 128; s > 0; s >>= 1) {
        if (t < s) ssum[t] += ssum[t + s];
        __syncthreads();
    }
    int b0 = ssum[0];
    int cntE = bcur[bucket];
    int p0 = bucket * CAP;

    // ---- load pairs + src-bucket histogram ----
    histA[t] = 0;
    histA[t + 256] = 0;
    __syncthreads();
    for (int j = t; j < cntE; j += 256) {
        u64 p = pair[p0 + j];
        prA[j] = p;
        atomicAdd(&histA[(int)(p & 0xffffu) >> BSH], 1);
    }
    __syncthreads();
    // ---- exclusive scan over 512 bins ----
    int h0 = histA[t], h1 = histA[t + 256];
    scA[t] = h0;
    scA[t + 256] = h1;
    __syncthreads();
    for (int off = 1; off < 512; off <<= 1) {
        int a0 = (t >= off) ? scA[t - off] : 0;
        int a1 = (t + 256 >= off) ? scA[t + 256 - off] : 0;
        __syncthreads();
        scA[t] += a0;
        scA[t + 256] += a1;
        __syncthreads();
    }
    histA[t] = scA[t] - h0;          // exclusive -> cursor
    histA[t + 256] = scA[t + 256] - h1;
    __syncthreads();
    // ---- scatter by src-bucket: prA -> prB ----
    for (int j = t; j < cntE; j += 256) {
        u64 p = prA[j];
        int pos = atomicAdd(&histA[(int)(p & 0xffffu) >> BSH], 1);
        prB[pos] = p;
    }
    __syncthreads();
    // ---- write back src-sorted pair (decode consumes this order) ----
    for (int j = t; j < cntE; j += 256) pair[p0 + j] = prB[j];

    // ---- pass B: loc counting sort from prB ----
    if (t < BSZ) cnt[t] = 0;
    __syncthreads();
    for (int j = t; j < cntE; j += 256)
        atomicAdd(&cnt[(int)((prB[j] >> 16) & (BSZ - 1))], 1);
    __syncthreads();
    if (t < BSZ) scn[t] = cnt[t];
    __syncthreads();
    for (int off = 1; off < BSZ; off <<= 1) {
        int a = (t < BSZ && t >= off) ? scn[t - off] : 0;
        __syncthreads();
        if (t < BSZ) scn[t] += a;
        __syncthreads();
    }
    if (t < nn) {
        int excl = b0 + scn[t] - cnt[t];
        row_ptr[base + t] = excl;
        cur[t] = excl;
        float d = (float)cnt[t] + 1.0f;
        dinv[base + t] = rsqrtf(d);
        inv[base + t] = 1.0f / d;
    }
    if (t == 0 && bucket == NBUCK - 1) row_ptr[n] = E;
    __syncthreads();
    for (int j = t; j < cntE; j += 256) {
        u64 p = prB[j];
        int ln = (int)((p >> 16) & (BSZ - 1));
        int pos = atomicAdd(&cur[ln], 1);
        col[pos] = (int)(p & 0xffffu);
    }
}

// ---------------- MFMA GEMM (layer 2): O(bf16) = X(bf16) @ W(f32) ----------------
template <int K, int NOUT>
__global__ __launch_bounds__(256) void gemm_mfma_bf(const u16* __restrict__ Xv,
                                                    const float* __restrict__ W,
                                                    u16* __restrict__ O, int n_rows) {
    constexpr int KP = K + 8;
    constexpr int NT = NOUT / 16;
    constexpr int KS = K / 32;
    __shared__ __align__(16) u16 Wt_hi[NOUT * KP];
    __shared__ __align__(16) u16 Wt_lo[NOUT * KP];
    int t = threadIdx.x;
    for (int i4 = t; i4 < K * NOUT / 4; i4 += 256) {
        int k = (i4 * 4) / NOUT;
        int n0 = (i4 * 4) % NOUT;
        float4 w4 = *(const float4*)&W[(size_t)k * NOUT + n0];
        float wv[4] = {w4.x, w4.y, w4.z, w4.w};
#pragma unroll
        for (int q = 0; q < 4; q++) {
            u32 hi = f2bf(wv[q]);
            u32 lo = f2bf(wv[q] - bflo(hi));
            Wt_hi[(n0 + q) * KP + k] = (u16)hi;
            Wt_lo[(n0 + q) * KP + k] = (u16)lo;
        }
    }
    __syncthreads();

    int wave = t >> 6;
    int lane = t & 63;
    int m16 = lane & 15;
    int quad = lane >> 4;
    int row0 = blockIdx.x * 128 + wave * 32;

    f32x4 acc[2][NT] = {};
    for (int ks = 0; ks < KS; ks++) {
        frag_u a_hi[2];
#pragma unroll
        for (int mt = 0; mt < 2; mt++) {
            int row = row0 + mt * 16 + m16;
            row = row < n_rows ? row : n_rows - 1;
            a_hi[mt].v = *(const uint4*)(Xv + (size_t)row * K + ks * 32 + quad * 8);
        }
#pragma unroll
        for (int nt = 0; nt < NT; nt++) {
            int n = nt * 16 + m16;
            frag_u b_hi, b_lo;
            b_hi.v = *(const uint4*)&Wt_hi[n * KP + ks * 32 + quad * 8];
            b_lo.v = *(const uint4*)&Wt_lo[n * KP + ks * 32 + quad * 8];
#pragma unroll
            for (int mt = 0; mt < 2; mt++) {
                acc[mt][nt] = __builtin_amdgcn_mfma_f32_16x16x32_bf16(a_hi[mt].f, b_hi.f, acc[mt][nt], 0, 0, 0);
                acc[mt][nt] = __builtin_amdgcn_mfma_f32_16x16x32_bf16(a_hi[mt].f, b_lo.f, acc[mt][nt], 0, 0, 0);
            }
        }
    }
#pragma unroll
    for (int mt = 0; mt < 2; mt++)
#pragma unroll
        for (int nt = 0; nt < NT; nt++)
#pragma unroll
            for (int r = 0; r < 4; r++) {
                int row = row0 + mt * 16 + quad * 4 + r;
                if (row < n_rows)
                    O[(size_t)row * NOUT + nt * 16 + m16] = (u16)f2bf(acc[mt][nt][r]);
            }
}

// ---------------- pull aggregation + self-loop + bias (+relu), bf16 in/out ----------------
// 16-deep gather pipeline (four 4-wide accumulate blocks at the same
// j-boundaries as the 4-wide baseline -> bit-identical f32 association);
// 8-wide and 4-wide remainder loops.
#define ACC4(va, vb, vc, vd, na, nb, nc, nd)                                          \
    acc[0] += bflo(va.x) * na + bflo(vb.x) * nb + bflo(vc.x) * nc + bflo(vd.x) * nd;  \
    acc[1] += bfhi(va.x) * na + bfhi(vb.x) * nb + bfhi(vc.x) * nc + bfhi(vd.x) * nd;  \
    acc[2] += bflo(va.y) * na + bflo(vb.y) * nb + bflo(vc.y) * nc + bflo(vd.y) * nd;  \
    acc[3] += bfhi(va.y) * na + bfhi(vb.y) * nb + bfhi(vc.y) * nc + bfhi(vd.y) * nd;  \
    acc[4] += bflo(va.z) * na + bflo(vb.z) * nb + bflo(vc.z) * nc + bflo(vd.z) * nd;  \
    acc[5] += bfhi(va.z) * na + bfhi(vb.z) * nb + bfhi(vc.z) * nc + bfhi(vd.z) * nd;  \
    acc[6] += bflo(va.w) * na + bflo(vb.w) * nb + bflo(vc.w) * nc + bflo(vd.w) * nd;  \
    acc[7] += bfhi(va.w) * na + bfhi(vb.w) * nb + bfhi(vc.w) * nc + bfhi(vd.w) * nd;

template <int C, bool RELU>
__global__ __launch_bounds__(256) void agg_pull(const u16* __restrict__ H,
                                                const int* __restrict__ row_ptr,
                                                const int* __restrict__ col,
                                                const float* __restrict__ dinv,
                                                const float* __restrict__ inv,
                                                const float* __restrict__ b,
                                                u16* __restrict__ O, int n) {
    constexpr int TPN = C / 8;
    const uint4* Hv = (const uint4*)H;
    int tid = blockIdx.x * 256 + threadIdx.x;
    int node = tid / TPN;
    if (node >= n) return;
    int part = tid % TPN;
    int c8 = part * 8;
    float dn = dinv[node];
    float iv = inv[node];
    float acc[8];
    {
        uint4 h = Hv[(size_t)node * TPN + part];
        acc[0] = bflo(h.x) * iv + b[c8 + 0];
        acc[1] = bfhi(h.x) * iv + b[c8 + 1];
        acc[2] = bflo(h.y) * iv + b[c8 + 2];
        acc[3] = bfhi(h.y) * iv + b[c8 + 3];
        acc[4] = bflo(h.z) * iv + b[c8 + 4];
        acc[5] = bfhi(h.z) * iv + b[c8 + 5];
        acc[6] = bflo(h.w) * iv + b[c8 + 6];
        acc[7] = bfhi(h.w) * iv + b[c8 + 7];
    }
    int j = row_ptr[node];
    int end = row_ptr[node + 1];
    for (; j + 15 < end; j += 16) {
        int s0 = col[j],      s1 = col[j + 1],  s2 = col[j + 2],  s3 = col[j + 3];
        int s4 = col[j + 4],  s5 = col[j + 5],  s6 = col[j + 6],  s7 = col[j + 7];
        int s8 = col[j + 8],  s9 = col[j + 9],  sa = col[j + 10], sb = col[j + 11];
        int sc = col[j + 12], sd = col[j + 13], se = col[j + 14], sf = col[j + 15];
        float n0 = dn * dinv[s0], n1 = dn * dinv[s1], n2 = dn * dinv[s2], n3 = dn * dinv[s3];
        float n4 = dn * dinv[s4], n5 = dn * dinv[s5], n6 = dn * dinv[s6], n7 = dn * dinv[s7];
        float n8 = dn * dinv[s8], n9 = dn * dinv[s9], na = dn * dinv[sa], nb = dn * dinv[sb];
        float nc = dn * dinv[sc], nd = dn * dinv[sd], ne = dn * dinv[se], nf = dn * dinv[sf];
        uint4 v0 = Hv[(size_t)s0 * TPN + part];
        uint4 v1 = Hv[(size_t)s1 * TPN + part];
        uint4 v2 = Hv[(size_t)s2 * TPN + part];
        uint4 v3 = Hv[(size_t)s3 * TPN + part];
        uint4 v4 = Hv[(size_t)s4 * TPN + part];
        uint4 v5 = Hv[(size_t)s5 * TPN + part];
        uint4 v6 = Hv[(size_t)s6 * TPN + part];
        uint4 v7 = Hv[(size_t)s7 * TPN + part];
        uint4 v8 = Hv[(size_t)s8 * TPN + part];
        uint4 v9 = Hv[(size_t)s9 * TPN + part];
        uint4 va = Hv[(size_t)sa * TPN + part];
        uint4 vb = Hv[(size_t)sb * TPN + part];
        uint4 vc = Hv[(size_t)sc * TPN + part];
        uint4 vd = Hv[(size_t)sd * TPN + part];
        uint4 ve = Hv[(size_t)se * TPN + part];
        uint4 vf = Hv[(size_t)sf * TPN + part];
        ACC4(v0, v1, v2, v3, n0, n1, n2, n3)
        ACC4(v4, v5, v6, v7, n4, n5, n6, n7)
        ACC4(v8, v9, va, vb, n8, n9, na, nb)
        ACC4(vc, vd, ve, vf, nc, nd, ne, nf)
    }
    for (; j + 7 < end; j += 8) {
        int s0 = col[j],     s1 = col[j + 1], s2 = col[j + 2], s3 = col[j + 3];
        int s4 = col[j + 4], s5 = col[j + 5], s6 = col[j + 6], s7 = col[j + 7];
        float n0 = dn * dinv[s0], n1 = dn * dinv[s1], n2 = dn * dinv[s2], n3 = dn * dinv[s3];
        float n4 = dn * dinv[s4], n5 = dn * dinv[s5], n6 = dn * dinv[s6], n7 = dn * dinv[s7];
        uint4 v0 = Hv[(size_t)s0 * TPN + part];
        uint4 v1 = Hv[(size_t)s1 * TPN + part];
        uint4 v2 = Hv[(size_t)s2 * TPN + part];
        uint4 v3 = Hv[(size_t)s3 * TPN + part];
        uint4 v4 = Hv[(size_t)s4 * TPN + part];
        uint4 v5 = Hv[(size_t)s5 * TPN + part];
        uint4 v6 = Hv[(size_t)s6 * TPN + part];
        uint4 v7 = Hv[(size_t)s7 * TPN + part];
        ACC4(v0, v1, v2, v3, n0, n1, n2, n3)
        ACC4(v4, v5, v6, v7, n4, n5, n6, n7)
    }
    for (; j + 3 < end; j += 4) {
        int s0 = col[j], s1 = col[j + 1], s2 = col[j + 2], s3 = col[j + 3];
        float n0 = dn * dinv[s0], n1 = dn * dinv[s1], n2 = dn * dinv[s2], n3 = dn * dinv[s3];
        uint4 v0 = Hv[(size_t)s0 * TPN + part];
        uint4 v1 = Hv[(size_t)s1 * TPN + part];
        uint4 v2 = Hv[(size_t)s2 * TPN + part];
        uint4 v3 = Hv[(size_t)s3 * TPN + part];
        ACC4(v0, v1, v2, v3, n0, n1, n2, n3)
    }
    for (; j < end; j++) {
        int s = col[j];
        float nm = dn * dinv[s];
        uint4 v = Hv[(size_t)s * TPN + part];
        acc[0] += bflo(v.x) * nm; acc[1] += bfhi(v.x) * nm;
        acc[2] += bflo(v.y) * nm; acc[3] += bfhi(v.y) * nm;
        acc[4] += bflo(v.z) * nm; acc[5] += bfhi(v.z) * nm;
        acc[6] += bflo(v.w) * nm; acc[7] += bfhi(v.w) * nm;
    }
    if (RELU) {
#pragma unroll
        for (int i = 0; i < 8; i++) acc[i] = fmaxf(acc[i], 0.f);
    }
    uint4 o;
    o.x = pack2(acc[0], acc[1]);
    o.y = pack2(acc[2], acc[3]);
    o.z = pack2(acc[4], acc[5]);
    o.w = pack2(acc[6], acc[7]);
    ((uint4*)O)[(size_t)node * TPN + part] = o;
}

// ---------------- decode with fused per-bucket Q-GEMM ----------------
// Per bucket: Q[128][64] = Z[bucket rows] @ Wb^T computed in LDS via MFMA,
// then edges walked from `pair` (SRC-SORTED -> Z gathers sweep), 2 edges per
// 8-lane group per iter: out[eid] = sigmoid(dot(Z[src], Q[dloc]) + bb).
__global__ __launch_bounds__(256) void decode_fused(const u16* __restrict__ Z,
                                                    const float* __restrict__ Wb,
                                                    const u64* __restrict__ pair,
                                                    const int* __restrict__ bcur,
                                                    const float* __restrict__ bb,
                                                    float* __restrict__ out, int n) {
    constexpr int K = 64, NOUT = 64;
    constexpr int KP = K + 8;   // 72
    constexpr int QP = 72;      // padded Q row (u16), 144B = 9 banks stagger
    __shared__ __align__(16) u16 Wt_hi[NOUT * KP];
    __shared__ __align__(16) u16 Wt_lo[NOUT * KP];
    __shared__ __align__(16) u16 Qs[BSZ * QP];
    int t = threadIdx.x;
    int bucket = blockIdx.x / DSPLIT;
    int part = blockIdx.x % DSPLIT;
    int base = bucket << BSH;

    // stage Wb^T hi/lo:  Wt[n*KP+k] <- split(Wb[n][k])   (Wb row-major [64][64])
    for (int i4 = t; i4 < K * NOUT / 4; i4 += 256) {
        int nn_ = (i4 * 4) / K;
        int k0 = (i4 * 4) % K;
        float4 w4 = *(const float4*)&Wb[(size_t)nn_ * K + k0];
        float wv[4] = {w4.x, w4.y, w4.z, w4.w};
#pragma unroll
        for (int q = 0; q < 4; q++) {
            u32 hi = f2bf(wv[q]);
            u32 lo = f2bf(wv[q] - bflo(hi));
            Wt_hi[nn_ * KP + k0 + q] = (u16)hi;
            Wt_lo[nn_ * KP + k0 + q] = (u16)lo;
        }
    }
    __syncthreads();

    // Q tile: 4 waves x 32 rows each, 64 cols, K=64 (2 ks steps)
    {
        int wave = t >> 6;
        int lane = t & 63;
        int m16 = lane & 15;
        int quad = lane >> 4;
        int row0 = wave * 32;
        f32x4 acc[2][4] = {};
        for (int ks = 0; ks < 2; ks++) {
            frag_u a[2];
#pragma unroll
            for (int mt = 0; mt < 2; mt++) {
                int node = base + row0 + mt * 16 + m16;
                node = node < n ? node : n - 1;
                a[mt].v = *(const uint4*)(Z + (size_t)node * K + ks * 32 + quad * 8);
            }
#pragma unroll
            for (int nt = 0; nt < 4; nt++) {
                int nc = nt * 16 + m16;
                frag_u b_hi, b_lo;
                b_hi.v = *(const uint4*)&Wt_hi[nc * KP + ks * 32 + quad * 8];
                b_lo.v = *(const uint4*)&Wt_lo[nc * KP + ks * 32 + quad * 8];
#pragma unroll
                for (int mt = 0; mt < 2; mt++) {
                    acc[mt][nt] = __builtin_amdgcn_mfma_f32_16x16x32_bf16(a[mt].f, b_hi.f, acc[mt][nt], 0, 0, 0);
                    acc[mt][nt] = __builtin_amdgcn_mfma_f32_16x16x32_bf16(a[mt].f, b_lo.f, acc[mt][nt], 0, 0, 0);
                }
            }
        }
#pragma unroll
        for (int mt = 0; mt < 2; mt++)
#pragma unroll
            for (int nt = 0; nt < 4; nt++)
#pragma unroll
                for (int r = 0; r < 4; r++) {
                    int rl = row0 + mt * 16 + quad * 4 + r;
                    Qs[rl * QP + nt * 16 + m16] = (u16)f2bf(acc[mt][nt][r]);
                }
    }
    __syncthreads();

    // edge walk: 2 edges per 8-lane group per iteration (src-sorted pair)
    const uint4* Zv = (const uint4*)Z;
    int cntE = bcur[bucket];
    int p0 = bucket * CAP;
    int chunk = (cntE + DSPLIT - 1) / DSPLIT;
    int s0 = part * chunk;
    int s1 = min(s0 + chunk, cntE);
    float bbv = bb[0];
    int lane8 = t & 7;
    int grp = t >> 3;   // 0..31
    for (int j = s0 + grp * 2; j < s1; j += 64) {
        u64 pA = pair[p0 + j];
        bool has2 = (j + 1) < s1;
        u64 pB = has2 ? pair[p0 + j + 1] : pA;
        int sA = (int)(pA & 0xffffu);
        int sB = (int)(pB & 0xffffu);
        int locA = (int)((pA >> 16) & (BSZ - 1));
        int locB = (int)((pB >> 16) & (BSZ - 1));
        uint4 zA = Zv[(size_t)sA * 8 + lane8];
        uint4 zB = Zv[(size_t)sB * 8 + lane8];
        uint4 qA = *(const uint4*)&Qs[locA * QP + lane8 * 8];
        uint4 qB = *(const uint4*)&Qs[locB * QP + lane8 * 8];
        float dA = bflo(zA.x) * bflo(qA.x) + bfhi(zA.x) * bfhi(qA.x)
                 + bflo(zA.y) * bflo(qA.y) + bfhi(zA.y) * bfhi(qA.y)
                 + bflo(zA.z) * bflo(qA.z) + bfhi(zA.z) * bfhi(qA.z)
                 + bflo(zA.w) * bflo(qA.w) + bfhi(zA.w) * bfhi(qA.w);
        float dB = bflo(zB.x) * bflo(qB.x) + bfhi(zB.x) * bfhi(qB.x)
                 + bflo(zB.y) * bflo(qB.y) + bfhi(zB.y) * bfhi(qB.y)
                 + bflo(zB.z) * bflo(qB.z) + bfhi(zB.z) * bfhi(qB.z)
                 + bflo(zB.w) * bflo(qB.w) + bfhi(zB.w) * bfhi(qB.w);
        dA += __shfl_down(dA, 4, 8);
        dA += __shfl_down(dA, 2, 8);
        dA += __shfl_down(dA, 1, 8);
        dB += __shfl_down(dB, 4, 8);
        dB += __shfl_down(dB, 2, 8);
        dB += __shfl_down(dB, 1, 8);
        if (lane8 == 0) {
            out[(int)(pA >> 32)] = 1.0f / (1.0f + expf(-(dA + bbv)));
            if (has2) out[(int)(pB >> 32)] = 1.0f / (1.0f + expf(-(dB + bbv)));
        }
    }
}

extern "C" void kernel_launch(void* const* d_in, const int* in_sizes, int n_in,
                              void* d_out, int out_size, void* d_ws, size_t ws_size,
                              hipStream_t stream) {
    const float* x  = (const float*)d_in[0];
    const int*   ei = (const int*)d_in[1];
    const float* W1 = (const float*)d_in[2];
    const float* b1 = (const float*)d_in[3];
    const float* W2 = (const float*)d_in[4];
    const float* b2 = (const float*)d_in[5];
    const float* Wb = (const float*)d_in[6];
    const float* bb = (const float*)d_in[7];
    float* out = (float*)d_out;

    const int N = N_NODES;
    const int E = in_sizes[1] / 2;
    const int* src = ei;
    const int* dst = ei + E;
    const int GBLK = (N + 127) / 128;        // 391 gemm blocks
    const int SBLK = (E + EPB - 1) / EPB;    // 196 scatter blocks

    // workspace layout
    char* w = (char*)d_ws;
    int*   bcur    = (int*)w;   w += (size_t)512 * 4;
    int*   row_ptr = (int*)w;   w += (size_t)(N + 1) * 4;
    int*   col     = (int*)w;   w += (size_t)E * 4;
    w = (char*)(((size_t)w + 15) & ~(size_t)15);
    u64*   pair    = (u64*)w;   w += (size_t)NBUCK * CAP * 8;
    float* dinv    = (float*)w; w += (size_t)N * 4;
    float* inv     = (float*)w; w += (size_t)N * 4;
    w = (char*)(((size_t)w + 15) & ~(size_t)15);
    u16* bufA = (u16*)w;        w += (size_t)N * 128 * 2;  // H1; later H2
    u16* bufB = (u16*)w;        w += (size_t)N * 128 * 2;  // h1
    u16* bufC = (u16*)w;                                   // Z

    u16* H1 = bufA;
    u16* h1 = bufB;
    u16* H2 = bufA;                  // H1 dead after agg1
    u16* Z  = bufC;

    // CSR build front-end overlapped with layer-1 GEMM (independent work)
    hipMemsetAsync(bcur, 0, 512 * 4, stream);
    gemm1_scatter<<<GBLK + SBLK, 256, 0, stream>>>(x, W1, H1, N, GBLK,
                                                   src, dst, bcur, pair, E);
    bucket_sort<<<NBUCK, 256, 0, stream>>>(pair, bcur, row_ptr, col, dinv, inv, N, E);

    // layer 1 aggregation
    agg_pull<128, true><<<((size_t)N * 16 + 255) / 256, 256, 0, stream>>>(
        H1, row_ptr, col, dinv, inv, b1, h1, N);

    // layer 2
    gemm_mfma_bf<128, 64><<<GBLK, 256, 0, stream>>>(h1, W2, H2, N);
    agg_pull<64, false><<<((size_t)N * 8 + 255) / 256, 256, 0, stream>>>(
        H2, row_ptr, col, dinv, inv, b2, Z, N);

    // decode: per-bucket fused Q-GEMM (LDS) + bilinear + sigmoid
    decode_fused<<<NBUCK * DSPLIT, 256, 0, stream>>>(Z, Wb, pair, bcur, bb, out, N);
}

// Round 8
// 219.134 us; speedup vs baseline: 1.2495x; 1.0946x over previous
//
#include <hip/hip_runtime.h>
#include <hip/hip_bf16.h>

// GAE: h1 = relu(gcn(x,W1,b1)); z = gcn(h1,W2,b2); out = sigmoid(dot(Z[src], Q[dst]) + bb)
// where Q = Z @ Wb^T  (bilinear refactor, dst-side precompute).
// PULL aggregation over on-device CSR; gathered node matrices bf16 ROW-major.
// GEMMs: MFMA bf16 split-hi/lo f32 emulation. CSR build: histogram-free
// fixed-capacity bucket scatter; gemm1 + bucket_scatter overlapped in one
// heterogeneous launch; bucket_sort inlines the 391-count prefix.
// Round 13: Q-GEMM fused into decode; pair carries eid. (232 us)
// Round 14 (plane-major) REGRESSED -> reverted (half-line fetches).
// Round 15: 8-deep gather MLP in agg; 2-edge decode walk. (229.5 us)
// Round 16: SRC-SORTED edge order (bucket_sort LDS counting sort by src>>7
// before loc sort). (223.7 us)
// Round 17 (phase-barriered windows) REGRESSED -> reverted (sync stragglers).
// Round 18 (16-deep agg, DSPLIT=8) REGRESSED 223.7->239.9: VGPR 28->84,
// occupancy 62->24% -- TLP beats ILP on latency-bound gathers. REVERTED to
// 8-deep agg + DSPLIT=4.
// Round 19: gemm2 FUSED into agg1 epilogue. Each agg1 block owns 16 complete
// h1 rows -> stage 16x128 tile in LDS (4.4KB), each wave computes one 16-col
// slice of H2 = h1@W2 (8 MFMAs, same ks/hi-lo order as gemm_mfma_bf ->
// bit-identical). W2 read direct from global (L2-hot). Deletes gemm2
// dispatch + 25.6MB h1 round-trip.
// Round 11 (persistent tail + spin barriers) regressed 4.3x (L2 thrash) - reverted.

#define N_NODES 50000
#define BSH 7
#define BSZ 128                             // nodes per bucket
#define NBUCK ((N_NODES + BSZ - 1) / BSZ)   // 391
#define EPB 4096                            // edges per scatter block
#define CAP 3072                            // pair slots per bucket (22 sigma over mean 2048)
#define DSPLIT 4                            // decode blocks per bucket

typedef unsigned int u32;
typedef unsigned short u16;
typedef unsigned long long u64;

typedef __attribute__((ext_vector_type(8))) short bf16x8;
typedef __attribute__((ext_vector_type(4))) float f32x4;
union frag_u { bf16x8 f; u32 u[4]; uint4 v; };

__device__ __forceinline__ float bflo(u32 u) { return __uint_as_float(u << 16); }
__device__ __forceinline__ float bfhi(u32 u) { return __uint_as_float(u & 0xffff0000u); }
__device__ __forceinline__ u32 f2bf(float f) {  // RNE, returns low 16
    u32 b = __float_as_uint(f);
    return (b + 0x7fffu + ((b >> 16) & 1u)) >> 16;
}
__device__ __forceinline__ u32 pack2(float a, float b) { return f2bf(a) | (f2bf(b) << 16); }

// ================= fused: gemm1 (blocks < gblk) | bucket_scatter (rest) =================
__global__ __launch_bounds__(256) void gemm1_scatter(
        const float* __restrict__ X, const float* __restrict__ W,
        u16* __restrict__ O, int n_rows, int gblk,
        const int* __restrict__ src, const int* __restrict__ dst,
        int* __restrict__ bcur, u64* __restrict__ pair, int E) {
    constexpr int K = 128, NOUT = 128;
    constexpr int KP = K + 8;
    constexpr int NT = NOUT / 16;
    constexpr int KS = K / 32;
    __shared__ __align__(16) char smem[NOUT * KP * 2 * sizeof(u16)];
    int t = threadIdx.x;

    if ((int)blockIdx.x < gblk) {
        // ---------------- gemm1 path ----------------
        u16* Wt_hi = (u16*)smem;
        u16* Wt_lo = Wt_hi + NOUT * KP;
        for (int i4 = t; i4 < K * NOUT / 4; i4 += 256) {
            int k = (i4 * 4) / NOUT;
            int n0 = (i4 * 4) % NOUT;
            float4 w4 = *(const float4*)&W[(size_t)k * NOUT + n0];
            float wv[4] = {w4.x, w4.y, w4.z, w4.w};
#pragma unroll
            for (int q = 0; q < 4; q++) {
                u32 hi = f2bf(wv[q]);
                u32 lo = f2bf(wv[q] - bflo(hi));
                Wt_hi[(n0 + q) * KP + k] = (u16)hi;
                Wt_lo[(n0 + q) * KP + k] = (u16)lo;
            }
        }
        __syncthreads();

        int wave = t >> 6;
        int lane = t & 63;
        int m16 = lane & 15;
        int quad = lane >> 4;
        int row0 = blockIdx.x * 128 + wave * 32;

        f32x4 acc[2][NT] = {};
        for (int ks = 0; ks < KS; ks++) {
            frag_u a_hi[2], a_lo[2];
#pragma unroll
            for (int mt = 0; mt < 2; mt++) {
                int row = row0 + mt * 16 + m16;
                row = row < n_rows ? row : n_rows - 1;
                const float* Xp = X + (size_t)row * K + ks * 32 + quad * 8;
                float4 x0 = *(const float4*)Xp;
                float4 x1 = *(const float4*)(Xp + 4);
                float xv[8] = {x0.x, x0.y, x0.z, x0.w, x1.x, x1.y, x1.z, x1.w};
#pragma unroll
                for (int p = 0; p < 4; p++) {
                    u32 h0 = f2bf(xv[2 * p]), h1 = f2bf(xv[2 * p + 1]);
                    a_hi[mt].u[p] = h0 | (h1 << 16);
                    a_lo[mt].u[p] = pack2(xv[2 * p] - bflo(h0), xv[2 * p + 1] - bflo(h1));
                }
            }
#pragma unroll
            for (int nt = 0; nt < NT; nt++) {
                int n = nt * 16 + m16;
                frag_u b_hi, b_lo;
                b_hi.v = *(const uint4*)&Wt_hi[n * KP + ks * 32 + quad * 8];
                b_lo.v = *(const uint4*)&Wt_lo[n * KP + ks * 32 + quad * 8];
#pragma unroll
                for (int mt = 0; mt < 2; mt++) {
                    acc[mt][nt] = __builtin_amdgcn_mfma_f32_16x16x32_bf16(a_hi[mt].f, b_hi.f, acc[mt][nt], 0, 0, 0);
                    acc[mt][nt] = __builtin_amdgcn_mfma_f32_16x16x32_bf16(a_hi[mt].f, b_lo.f, acc[mt][nt], 0, 0, 0);
                    acc[mt][nt] = __builtin_amdgcn_mfma_f32_16x16x32_bf16(a_lo[mt].f, b_hi.f, acc[mt][nt], 0, 0, 0);
                }
            }
        }
#pragma unroll
        for (int mt = 0; mt < 2; mt++)
#pragma unroll
            for (int nt = 0; nt < NT; nt++)
#pragma unroll
                for (int r = 0; r < 4; r++) {
                    int row = row0 + mt * 16 + quad * 4 + r;
                    if (row < n_rows)
                        O[(size_t)row * NOUT + nt * 16 + m16] = (u16)f2bf(acc[mt][nt][r]);
                }
    } else {
        // ---------------- scatter path ----------------
        int* hist = (int*)smem;
        for (int i = t; i < NBUCK; i += 256) hist[i] = 0;
        __syncthreads();
        int base = ((int)blockIdx.x - gblk) * EPB;
        int s_[16], d_[16];
#pragma unroll
        for (int it = 0; it < 16; it++) {
            int e = base + it * 256 + t;
            if (e < E) {
                s_[it] = src[e];
                d_[it] = dst[e];
                atomicAdd(&hist[d_[it] >> BSH], 1);
            } else {
                d_[it] = -1;
            }
        }
        __syncthreads();
        for (int b = t; b < NBUCK; b += 256) {
            int c = hist[b];
            hist[b] = c ? (b * CAP + atomicAdd(&bcur[b], c)) : 0;  // absolute chunk base
        }
        __syncthreads();
#pragma unroll
        for (int it = 0; it < 16; it++) {
            if (d_[it] >= 0) {
                int b = d_[it] >> BSH;
                int off = atomicAdd(&hist[b], 1);
                int e = base + it * 256 + t;
                pair[off] = (u64)((u32)s_[it] | ((u32)(d_[it] & (BSZ - 1)) << 16))
                          | ((u64)(u32)e << 32);
            }
        }
    }
}

// ---------------- per-bucket: src-bucket sort + loc sort + row_ptr/dinv/inv ----------------
__global__ __launch_bounds__(256) void bucket_sort(u64* __restrict__ pair,
                                                   const int* __restrict__ bcur,
                                                   int* __restrict__ row_ptr,
                                                   int* __restrict__ col,
                                                   float* __restrict__ dinv,
                                                   float* __restrict__ inv, int n, int E) {
    __shared__ u64 prA[CAP];     // 24KB
    __shared__ u64 prB[CAP];     // 24KB
    __shared__ int ssum[256];
    __shared__ int histA[512];
    __shared__ int scA[512];
    __shared__ int cnt[BSZ];
    __shared__ int scn[BSZ];
    __shared__ int cur[BSZ];
    int t = threadIdx.x;
    int bucket = blockIdx.x;
    int base = bucket << BSH;
    int nn = min(BSZ, n - base);
    // inline exclusive prefix: b0 = sum(bcur[0..bucket-1])
    int accp = 0;
    for (int i = t; i < bucket; i += 256) accp += bcur[i];
    ssum[t] = accp;
    __syncthreads();
    for (int s = 128; s > 0; s >>= 1) {
        if (t < s) ssum[t] += ssum[t + s];
        __syncthreads();
    }
    int b0 = ssum[0];
    int cntE = bcur[bucket];
    int p0 = bucket * CAP;

    // ---- load pairs + src-bucket histogram ----
    histA[t] = 0;
    histA[t + 256] = 0;
    __syncthreads();
    for (int j = t; j < cntE; j += 256) {
        u64 p = pair[p0 + j];
        prA[j] = p;
        atomicAdd(&histA[(int)(p & 0xffffu) >> BSH], 1);
    }
    __syncthreads();
    // ---- exclusive scan over 512 bins ----
    int h0 = histA[t], h1 = histA[t + 256];
    scA[t] = h0;
    scA[t + 256] = h1;
    __syncthreads();
    for (int off = 1; off < 512; off <<= 1) {
        int a0 = (t >= off) ? scA[t - off] : 0;
        int a1 = (t + 256 >= off) ? scA[t + 256 - off] : 0;
        __syncthreads();
        scA[t] += a0;
        scA[t + 256] += a1;
        __syncthreads();
    }
    histA[t] = scA[t] - h0;          // exclusive -> cursor
    histA[t + 256] = scA[t + 256] - h1;
    __syncthreads();
    // ---- scatter by src-bucket: prA -> prB ----
    for (int j = t; j < cntE; j += 256) {
        u64 p = prA[j];
        int pos = atomicAdd(&histA[(int)(p & 0xffffu) >> BSH], 1);
        prB[pos] = p;
    }
    __syncthreads();
    // ---- write back src-sorted pair (decode consumes this order) ----
    for (int j = t; j < cntE; j += 256) pair[p0 + j] = prB[j];

    // ---- pass B: loc counting sort from prB ----
    if (t < BSZ) cnt[t] = 0;
    __syncthreads();
    for (int j = t; j < cntE; j += 256)
        atomicAdd(&cnt[(int)((prB[j] >> 16) & (BSZ - 1))], 1);
    __syncthreads();
    if (t < BSZ) scn[t] = cnt[t];
    __syncthreads();
    for (int off = 1; off < BSZ; off <<= 1) {
        int a = (t < BSZ && t >= off) ? scn[t - off] : 0;
        __syncthreads();
        if (t < BSZ) scn[t] += a;
        __syncthreads();
    }
    if (t < nn) {
        int excl = b0 + scn[t] - cnt[t];
        row_ptr[base + t] = excl;
        cur[t] = excl;
        float d = (float)cnt[t] + 1.0f;
        dinv[base + t] = rsqrtf(d);
        inv[base + t] = 1.0f / d;
    }
    if (t == 0 && bucket == NBUCK - 1) row_ptr[n] = E;
    __syncthreads();
    for (int j = t; j < cntE; j += 256) {
        u64 p = prB[j];
        int ln = (int)((p >> 16) & (BSZ - 1));
        int pos = atomicAdd(&cur[ln], 1);
        col[pos] = (int)(p & 0xffffu);
    }
}

#define ACC4(va, vb, vc, vd, na, nb, nc, nd)                                          \
    acc[0] += bflo(va.x) * na + bflo(vb.x) * nb + bflo(vc.x) * nc + bflo(vd.x) * nd;  \
    acc[1] += bfhi(va.x) * na + bfhi(vb.x) * nb + bfhi(vc.x) * nc + bfhi(vd.x) * nd;  \
    acc[2] += bflo(va.y) * na + bflo(vb.y) * nb + bflo(vc.y) * nc + bflo(vd.y) * nd;  \
    acc[3] += bfhi(va.y) * na + bfhi(vb.y) * nb + bfhi(vc.y) * nc + bfhi(vd.y) * nd;  \
    acc[4] += bflo(va.z) * na + bflo(vb.z) * nb + bflo(vc.z) * nc + bflo(vd.z) * nd;  \
    acc[5] += bfhi(va.z) * na + bfhi(vb.z) * nb + bfhi(vc.z) * nc + bfhi(vd.z) * nd;  \
    acc[6] += bflo(va.w) * na + bflo(vb.w) * nb + bflo(vc.w) * nc + bflo(vd.w) * nd;  \
    acc[7] += bfhi(va.w) * na + bfhi(vb.w) * nb + bfhi(vc.w) * nc + bfhi(vd.w) * nd;

// ---------------- agg1 + gemm2 fused: H2 = relu(agg(H1)+b1) @ W2 ----------------
// Gather part identical to round-15 8-deep agg_pull<128,true>. Epilogue: the
// block's 16 complete h1 rows staged in LDS (bf16, same values as the old
// h1 buffer), then each wave computes one 16-col slice of H2 = h1_tile @ W2
// (ks-major, hi-then-lo 2-term MFMA chain == gemm_mfma_bf<128,64> order ->
// bit-identical). W2 read direct from global (32KB, L2-hot).
__global__ __launch_bounds__(256) void agg1_gemm2(const u16* __restrict__ H,
                                                  const int* __restrict__ row_ptr,
                                                  const int* __restrict__ col,
                                                  const float* __restrict__ dinv,
                                                  const float* __restrict__ inv,
                                                  const float* __restrict__ b,
                                                  const float* __restrict__ W2,
                                                  u16* __restrict__ H2, int n) {
    constexpr int TPN = 16;  // threads per node (128 ch / 8)
    __shared__ __align__(16) u16 h1s[16][136];
    const uint4* Hv = (const uint4*)H;
    int t = threadIdx.x;
    int tid = blockIdx.x * 256 + t;
    int node = tid / TPN;    // grid sized so node < n always (n % 16 == 0)
    int part = tid % TPN;
    int c8 = part * 8;
    float dn = dinv[node];
    float iv = inv[node];
    float acc[8];
    {
        uint4 h = Hv[(size_t)node * TPN + part];
        acc[0] = bflo(h.x) * iv + b[c8 + 0];
        acc[1] = bfhi(h.x) * iv + b[c8 + 1];
        acc[2] = bflo(h.y) * iv + b[c8 + 2];
        acc[3] = bfhi(h.y) * iv + b[c8 + 3];
        acc[4] = bflo(h.z) * iv + b[c8 + 4];
        acc[5] = bfhi(h.z) * iv + b[c8 + 5];
        acc[6] = bflo(h.w) * iv + b[c8 + 6];
        acc[7] = bfhi(h.w) * iv + b[c8 + 7];
    }
    int j = row_ptr[node];
    int end = row_ptr[node + 1];
    for (; j + 7 < end; j += 8) {
        int s0 = col[j],     s1 = col[j + 1], s2 = col[j + 2], s3 = col[j + 3];
        int s4 = col[j + 4], s5 = col[j + 5], s6 = col[j + 6], s7 = col[j + 7];
        float n0 = dn * dinv[s0], n1 = dn * dinv[s1], n2 = dn * dinv[s2], n3 = dn * dinv[s3];
        float n4 = dn * dinv[s4], n5 = dn * dinv[s5], n6 = dn * dinv[s6], n7 = dn * dinv[s7];
        uint4 v0 = Hv[(size_t)s0 * TPN + part];
        uint4 v1 = Hv[(size_t)s1 * TPN + part];
        uint4 v2 = Hv[(size_t)s2 * TPN + part];
        uint4 v3 = Hv[(size_t)s3 * TPN + part];
        uint4 v4 = Hv[(size_t)s4 * TPN + part];
        uint4 v5 = Hv[(size_t)s5 * TPN + part];
        uint4 v6 = Hv[(size_t)s6 * TPN + part];
        uint4 v7 = Hv[(size_t)s7 * TPN + part];
        ACC4(v0, v1, v2, v3, n0, n1, n2, n3)
        ACC4(v4, v5, v6, v7, n4, n5, n6, n7)
    }
    for (; j + 3 < end; j += 4) {
        int s0 = col[j], s1 = col[j + 1], s2 = col[j + 2], s3 = col[j + 3];
        float n0 = dn * dinv[s0], n1 = dn * dinv[s1], n2 = dn * dinv[s2], n3 = dn * dinv[s3];
        uint4 v0 = Hv[(size_t)s0 * TPN + part];
        uint4 v1 = Hv[(size_t)s1 * TPN + part];
        uint4 v2 = Hv[(size_t)s2 * TPN + part];
        uint4 v3 = Hv[(size_t)s3 * TPN + part];
        ACC4(v0, v1, v2, v3, n0, n1, n2, n3)
    }
    for (; j < end; j++) {
        int s = col[j];
        float nm = dn * dinv[s];
        uint4 v = Hv[(size_t)s * TPN + part];
        acc[0] += bflo(v.x) * nm; acc[1] += bfhi(v.x) * nm;
        acc[2] += bflo(v.y) * nm; acc[3] += bfhi(v.y) * nm;
        acc[4] += bflo(v.z) * nm; acc[5] += bfhi(v.z) * nm;
        acc[6] += bflo(v.w) * nm; acc[7] += bfhi(v.w) * nm;
    }
#pragma unroll
    for (int i = 0; i < 8; i++) acc[i] = fmaxf(acc[i], 0.f);
    uint4 o;
    o.x = pack2(acc[0], acc[1]);
    o.y = pack2(acc[2], acc[3]);
    o.z = pack2(acc[4], acc[5]);
    o.w = pack2(acc[6], acc[7]);
    *(uint4*)&h1s[t >> 4][c8] = o;   // node_local = t/16
    __syncthreads();

    // ---- epilogue: H2[16][64] = h1s @ W2, wave w owns cols [w*16, w*16+16) ----
    int wave = t >> 6;
    int lane = t & 63;
    int m16 = lane & 15;
    int quad = lane >> 4;
    int ncol = wave * 16 + m16;
    f32x4 acc2 = {};
#pragma unroll
    for (int ks = 0; ks < 4; ks++) {
        frag_u a, bh, bl;
        a.v = *(const uint4*)&h1s[m16][ks * 32 + quad * 8];
        const float* Wp = W2 + (size_t)(ks * 32 + quad * 8) * 64 + ncol;
        float w0 = Wp[0 * 64], w1 = Wp[1 * 64], w2 = Wp[2 * 64], w3 = Wp[3 * 64];
        float w4 = Wp[4 * 64], w5 = Wp[5 * 64], w6 = Wp[6 * 64], w7 = Wp[7 * 64];
        u32 h0 = f2bf(w0), h1 = f2bf(w1), h2 = f2bf(w2), h3 = f2bf(w3);
        u32 h4 = f2bf(w4), h5 = f2bf(w5), h6 = f2bf(w6), h7 = f2bf(w7);
        bh.u[0] = h0 | (h1 << 16);
        bh.u[1] = h2 | (h3 << 16);
        bh.u[2] = h4 | (h5 << 16);
        bh.u[3] = h6 | (h7 << 16);
        bl.u[0] = pack2(w0 - bflo(h0), w1 - bflo(h1));
        bl.u[1] = pack2(w2 - bflo(h2), w3 - bflo(h3));
        bl.u[2] = pack2(w4 - bflo(h4), w5 - bflo(h5));
        bl.u[3] = pack2(w6 - bflo(h6), w7 - bflo(h7));
        acc2 = __builtin_amdgcn_mfma_f32_16x16x32_bf16(a.f, bh.f, acc2, 0, 0, 0);
        acc2 = __builtin_amdgcn_mfma_f32_16x16x32_bf16(a.f, bl.f, acc2, 0, 0, 0);
    }
    int rowbase = blockIdx.x * 16 + quad * 4;
#pragma unroll
    for (int r = 0; r < 4; r++)
        H2[(size_t)(rowbase + r) * 64 + ncol] = (u16)f2bf(acc2[r]);
}

// ---------------- pull aggregation + self-loop + bias, bf16 in/out (layer 2) ----------------
template <int C, bool RELU>
__global__ __launch_bounds__(256) void agg_pull(const u16* __restrict__ H,
                                                const int* __restrict__ row_ptr,
                                                const int* __restrict__ col,
                                                const float* __restrict__ dinv,
                                                const float* __restrict__ inv,
                                                const float* __restrict__ b,
                                                u16* __restrict__ O, int n) {
    constexpr int TPN = C / 8;
    const uint4* Hv = (const uint4*)H;
    int tid = blockIdx.x * 256 + threadIdx.x;
    int node = tid / TPN;
    if (node >= n) return;
    int part = tid % TPN;
    int c8 = part * 8;
    float dn = dinv[node];
    float iv = inv[node];
    float acc[8];
    {
        uint4 h = Hv[(size_t)node * TPN + part];
        acc[0] = bflo(h.x) * iv + b[c8 + 0];
        acc[1] = bfhi(h.x) * iv + b[c8 + 1];
        acc[2] = bflo(h.y) * iv + b[c8 + 2];
        acc[3] = bfhi(h.y) * iv + b[c8 + 3];
        acc[4] = bflo(h.z) * iv + b[c8 + 4];
        acc[5] = bfhi(h.z) * iv + b[c8 + 5];
        acc[6] = bflo(h.w) * iv + b[c8 + 6];
        acc[7] = bfhi(h.w) * iv + b[c8 + 7];
    }
    int j = row_ptr[node];
    int end = row_ptr[node + 1];
    for (; j + 7 < end; j += 8) {
        int s0 = col[j],     s1 = col[j + 1], s2 = col[j + 2], s3 = col[j + 3];
        int s4 = col[j + 4], s5 = col[j + 5], s6 = col[j + 6], s7 = col[j + 7];
        float n0 = dn * dinv[s0], n1 = dn * dinv[s1], n2 = dn * dinv[s2], n3 = dn * dinv[s3];
        float n4 = dn * dinv[s4], n5 = dn * dinv[s5], n6 = dn * dinv[s6], n7 = dn * dinv[s7];
        uint4 v0 = Hv[(size_t)s0 * TPN + part];
        uint4 v1 = Hv[(size_t)s1 * TPN + part];
        uint4 v2 = Hv[(size_t)s2 * TPN + part];
        uint4 v3 = Hv[(size_t)s3 * TPN + part];
        uint4 v4 = Hv[(size_t)s4 * TPN + part];
        uint4 v5 = Hv[(size_t)s5 * TPN + part];
        uint4 v6 = Hv[(size_t)s6 * TPN + part];
        uint4 v7 = Hv[(size_t)s7 * TPN + part];
        ACC4(v0, v1, v2, v3, n0, n1, n2, n3)
        ACC4(v4, v5, v6, v7, n4, n5, n6, n7)
    }
    for (; j + 3 < end; j += 4) {
        int s0 = col[j], s1 = col[j + 1], s2 = col[j + 2], s3 = col[j + 3];
        float n0 = dn * dinv[s0], n1 = dn * dinv[s1], n2 = dn * dinv[s2], n3 = dn * dinv[s3];
        uint4 v0 = Hv[(size_t)s0 * TPN + part];
        uint4 v1 = Hv[(size_t)s1 * TPN + part];
        uint4 v2 = Hv[(size_t)s2 * TPN + part];
        uint4 v3 = Hv[(size_t)s3 * TPN + part];
        ACC4(v0, v1, v2, v3, n0, n1, n2, n3)
    }
    for (; j < end; j++) {
        int s = col[j];
        float nm = dn * dinv[s];
        uint4 v = Hv[(size_t)s * TPN + part];
        acc[0] += bflo(v.x) * nm; acc[1] += bfhi(v.x) * nm;
        acc[2] += bflo(v.y) * nm; acc[3] += bfhi(v.y) * nm;
        acc[4] += bflo(v.z) * nm; acc[5] += bfhi(v.z) * nm;
        acc[6] += bflo(v.w) * nm; acc[7] += bfhi(v.w) * nm;
    }
    if (RELU) {
#pragma unroll
        for (int i = 0; i < 8; i++) acc[i] = fmaxf(acc[i], 0.f);
    }
    uint4 o;
    o.x = pack2(acc[0], acc[1]);
    o.y = pack2(acc[2], acc[3]);
    o.z = pack2(acc[4], acc[5]);
    o.w = pack2(acc[6], acc[7]);
    ((uint4*)O)[(size_t)node * TPN + part] = o;
}

// ---------------- decode with fused per-bucket Q-GEMM ----------------
__global__ __launch_bounds__(256) void decode_fused(const u16* __restrict__ Z,
                                                    const float* __restrict__ Wb,
                                                    const u64* __restrict__ pair,
                                                    const int* __restrict__ bcur,
                                                    const float* __restrict__ bb,
                                                    float* __restrict__ out, int n) {
    constexpr int K = 64, NOUT = 64;
    constexpr int KP = K + 8;   // 72
    constexpr int QP = 72;      // padded Q row (u16), 144B = 9 banks stagger
    __shared__ __align__(16) u16 Wt_hi[NOUT * KP];
    __shared__ __align__(16) u16 Wt_lo[NOUT * KP];
    __shared__ __align__(16) u16 Qs[BSZ * QP];
    int t = threadIdx.x;
    int bucket = blockIdx.x / DSPLIT;
    int part = blockIdx.x % DSPLIT;
    int base = bucket << BSH;

    // stage Wb^T hi/lo:  Wt[n*KP+k] <- split(Wb[n][k])   (Wb row-major [64][64])
    for (int i4 = t; i4 < K * NOUT / 4; i4 += 256) {
        int nn_ = (i4 * 4) / K;
        int k0 = (i4 * 4) % K;
        float4 w4 = *(const float4*)&Wb[(size_t)nn_ * K + k0];
        float wv[4] = {w4.x, w4.y, w4.z, w4.w};
#pragma unroll
        for (int q = 0; q < 4; q++) {
            u32 hi = f2bf(wv[q]);
            u32 lo = f2bf(wv[q] - bflo(hi));
            Wt_hi[nn_ * KP + k0 + q] = (u16)hi;
            Wt_lo[nn_ * KP + k0 + q] = (u16)lo;
        }
    }
    __syncthreads();

    // Q tile: 4 waves x 32 rows each, 64 cols, K=64 (2 ks steps)
    {
        int wave = t >> 6;
        int lane = t & 63;
        int m16 = lane & 15;
        int quad = lane >> 4;
        int row0 = wave * 32;
        f32x4 acc[2][4] = {};
        for (int ks = 0; ks < 2; ks++) {
            frag_u a[2];
#pragma unroll
            for (int mt = 0; mt < 2; mt++) {
                int node = base + row0 + mt * 16 + m16;
                node = node < n ? node : n - 1;
                a[mt].v = *(const uint4*)(Z + (size_t)node * K + ks * 32 + quad * 8);
            }
#pragma unroll
            for (int nt = 0; nt < 4; nt++) {
                int nc = nt * 16 + m16;
                frag_u b_hi, b_lo;
                b_hi.v = *(const uint4*)&Wt_hi[nc * KP + ks * 32 + quad * 8];
                b_lo.v = *(const uint4*)&Wt_lo[nc * KP + ks * 32 + quad * 8];
#pragma unroll
                for (int mt = 0; mt < 2; mt++) {
                    acc[mt][nt] = __builtin_amdgcn_mfma_f32_16x16x32_bf16(a[mt].f, b_hi.f, acc[mt][nt], 0, 0, 0);
                    acc[mt][nt] = __builtin_amdgcn_mfma_f32_16x16x32_bf16(a[mt].f, b_lo.f, acc[mt][nt], 0, 0, 0);
                }
            }
        }
#pragma unroll
        for (int mt = 0; mt < 2; mt++)
#pragma unroll
            for (int nt = 0; nt < 4; nt++)
#pragma unroll
                for (int r = 0; r < 4; r++) {
                    int rl = row0 + mt * 16 + quad * 4 + r;
                    Qs[rl * QP + nt * 16 + m16] = (u16)f2bf(acc[mt][nt][r]);
                }
    }
    __syncthreads();

    // edge walk: 2 edges per 8-lane group per iteration (src-sorted pair)
    const uint4* Zv = (const uint4*)Z;
    int cntE = bcur[bucket];
    int p0 = bucket * CAP;
    int chunk = (cntE + DSPLIT - 1) / DSPLIT;
    int s0 = part * chunk;
    int s1 = min(s0 + chunk, cntE);
    float bbv = bb[0];
    int lane8 = t & 7;
    int grp = t >> 3;   // 0..31
    for (int j = s0 + grp * 2; j < s1; j += 64) {
        u64 pA = pair[p0 + j];
        bool has2 = (j + 1) < s1;
        u64 pB = has2 ? pair[p0 + j + 1] : pA;
        int sA = (int)(pA & 0xffffu);
        int sB = (int)(pB & 0xffffu);
        int locA = (int)((pA >> 16) & (BSZ - 1));
        int locB = (int)((pB >> 16) & (BSZ - 1));
        uint4 zA = Zv[(size_t)sA * 8 + lane8];
        uint4 zB = Zv[(size_t)sB * 8 + lane8];
        uint4 qA = *(const uint4*)&Qs[locA * QP + lane8 * 8];
        uint4 qB = *(const uint4*)&Qs[locB * QP + lane8 * 8];
        float dA = bflo(zA.x) * bflo(qA.x) + bfhi(zA.x) * bfhi(qA.x)
                 + bflo(zA.y) * bflo(qA.y) + bfhi(zA.y) * bfhi(qA.y)
                 + bflo(zA.z) * bflo(qA.z) + bfhi(zA.z) * bfhi(qA.z)
                 + bflo(zA.w) * bflo(qA.w) + bfhi(zA.w) * bfhi(qA.w);
        float dB = bflo(zB.x) * bflo(qB.x) + bfhi(zB.x) * bfhi(qB.x)
                 + bflo(zB.y) * bflo(qB.y) + bfhi(zB.y) * bfhi(qB.y)
                 + bflo(zB.z) * bflo(qB.z) + bfhi(zB.z) * bfhi(qB.z)
                 + bflo(zB.w) * bflo(qB.w) + bfhi(zB.w) * bfhi(qB.w);
        dA += __shfl_down(dA, 4, 8);
        dA += __shfl_down(dA, 2, 8);
        dA += __shfl_down(dA, 1, 8);
        dB += __shfl_down(dB, 4, 8);
        dB += __shfl_down(dB, 2, 8);
        dB += __shfl_down(dB, 1, 8);
        if (lane8 == 0) {
            out[(int)(pA >> 32)] = 1.0f / (1.0f + expf(-(dA + bbv)));
            if (has2) out[(int)(pB >> 32)] = 1.0f / (1.0f + expf(-(dB + bbv)));
        }
    }
}

extern "C" void kernel_launch(void* const* d_in, const int* in_sizes, int n_in,
                              void* d_out, int out_size, void* d_ws, size_t ws_size,
                              hipStream_t stream) {
    const float* x  = (const float*)d_in[0];
    const int*   ei = (const int*)d_in[1];
    const float* W1 = (const float*)d_in[2];
    const float* b1 = (const float*)d_in[3];
    const float* W2 = (const float*)d_in[4];
    const float* b2 = (const float*)d_in[5];
    const float* Wb = (const float*)d_in[6];
    const float* bb = (const float*)d_in[7];
    float* out = (float*)d_out;

    const int N = N_NODES;
    const int E = in_sizes[1] / 2;
    const int* src = ei;
    const int* dst = ei + E;
    const int GBLK = (N + 127) / 128;        // 391 gemm blocks
    const int SBLK = (E + EPB - 1) / EPB;    // 196 scatter blocks

    // workspace layout
    char* w = (char*)d_ws;
    int*   bcur    = (int*)w;   w += (size_t)512 * 4;
    int*   row_ptr = (int*)w;   w += (size_t)(N + 1) * 4;
    int*   col     = (int*)w;   w += (size_t)E * 4;
    w = (char*)(((size_t)w + 15) & ~(size_t)15);
    u64*   pair    = (u64*)w;   w += (size_t)NBUCK * CAP * 8;
    float* dinv    = (float*)w; w += (size_t)N * 4;
    float* inv     = (float*)w; w += (size_t)N * 4;
    w = (char*)(((size_t)w + 15) & ~(size_t)15);
    u16* bufA = (u16*)w;        w += (size_t)N * 128 * 2;  // H1
    u16* bufB = (u16*)w;        w += (size_t)N * 128 * 2;  // H2
    u16* bufC = (u16*)w;                                   // Z

    u16* H1 = bufA;
    u16* H2 = bufB;
    u16* Z  = bufC;

    // CSR build front-end overlapped with layer-1 GEMM (independent work)
    hipMemsetAsync(bcur, 0, 512 * 4, stream);
    gemm1_scatter<<<GBLK + SBLK, 256, 0, stream>>>(x, W1, H1, N, GBLK,
                                                   src, dst, bcur, pair, E);
    bucket_sort<<<NBUCK, 256, 0, stream>>>(pair, bcur, row_ptr, col, dinv, inv, N, E);

    // layer 1 aggregation + layer-2 GEMM fused (h1 never hits memory)
    agg1_gemm2<<<((size_t)N * 16 + 255) / 256, 256, 0, stream>>>(
        H1, row_ptr, col, dinv, inv, b1, W2, H2, N);

    // layer 2 aggregation
    agg_pull<64, false><<<((size_t)N * 8 + 255) / 256, 256, 0, stream>>>(
        H2, row_ptr, col, dinv, inv, b2, Z, N);

    // decode: per-bucket fused Q-GEMM (LDS) + bilinear + sigmoid
    decode_fused<<<NBUCK * DSPLIT, 256, 0, stream>>>(Z, Wb, pair, bcur, bb, out, N);
}